// Round 5
// baseline (241.892 us; speedup 1.0000x reference)
//
#include <hip/hip_runtime.h>
#include <hip/hip_bf16.h>
#include <math.h>

// ---- problem constants ----
#define BROWS 16384
#define NF    10
#define EMB   32
#define DENSE 16
#define K0S   352   // 336 padded to 11 K-steps of 32
#define K0    336
#define N0    256
#define N1    128
#define N2    64
#define BN_INV 0.99999500003749969f  // 1/sqrt(1+1e-5)

__constant__ int c_offsets[NF] = {
    0, 1000000, 1100000, 1101008, 1102012,
    1102114, 1103114, 1103614, 1103664, 1103776
};

typedef short  bf16x8 __attribute__((ext_vector_type(8)));
typedef float  f32x4  __attribute__((ext_vector_type(4)));

union Frag { bf16x8 v; unsigned u[4]; };

static __device__ __forceinline__ unsigned short f2bf(float x) {
    union { float f; unsigned u; } c; c.f = x;
    unsigned r = (c.u + 0x7FFFu + ((c.u >> 16) & 1u)) >> 16;  // RNE
    return (unsigned short)r;
}
// hw v_cvt_pk_bf16_f32 on gfx950 (RNE)
static __device__ __forceinline__ unsigned pk2(float x, float y) {
    __hip_bfloat162 h = __float22bfloat162_rn(make_float2(x, y));
    union { __hip_bfloat162 h; unsigned u; } c; c.h = h; return c.u;
}

// ---------------------------------------------------------------------------
// Weight fp32 -> bf16 conversion (W0 K-padded 336->352). 131072 elements.
// ---------------------------------------------------------------------------
__global__ __launch_bounds__(256) void k_wconv_all(
    const float* __restrict__ W0, const float* __restrict__ W1,
    const float* __restrict__ W2,
    unsigned short* __restrict__ W0b, unsigned short* __restrict__ W1b,
    unsigned short* __restrict__ W2b)
{
    int i = blockIdx.x * 256 + threadIdx.x;
    if (i < N0 * K0S) {
        int r = i / K0S, c = i - r * K0S;
        W0b[i] = f2bf(c < K0 ? W0[r * K0 + c] : 0.f);
    } else if (i < N0 * K0S + N1 * N0) {
        int j = i - N0 * K0S;
        W1b[j] = f2bf(W1[j]);
    } else {
        int j = i - (N0 * K0S + N1 * N0);
        W2b[j] = f2bf(W2[j]);
    }
}

// ---------------------------------------------------------------------------
// Single fused kernel: gather + FM + L0 + L1 + L2 + out-dot + sigmoid.
// block = 256 thr = 4 waves, 16 batch rows per block, grid = 1024.
// Each wave: all 16 rows, one QUARTER of the output columns per layer
// (redundant A-side gathers across the 4 waves hit L1).
// MFMA 16x16x32 bf16: A[m=l16][k=quad*8+j]; B-frag = W[n=l16][k=...];
// C/D: col=l16, row=quad*4+reg.
// ---------------------------------------------------------------------------
__global__ __launch_bounds__(256) void k_fused_all(
    const int*   __restrict__ sparse,    // [B, NF]
    const float* __restrict__ dense,     // [B, DENSE]
    const float* __restrict__ emb,       // [V, EMB]
    const float* __restrict__ bias_tab,  // [V]
    const float* __restrict__ fm_bias,   // [1]
    const unsigned short* __restrict__ W0b,  // [N0, K0S]
    const float* __restrict__ b0, const float* __restrict__ g0,
    const float* __restrict__ be0,
    const unsigned short* __restrict__ W1b,  // [N1, N0]
    const float* __restrict__ b1, const float* __restrict__ g1,
    const float* __restrict__ be1,
    const unsigned short* __restrict__ W2b,  // [N2, N1]
    const float* __restrict__ b2, const float* __restrict__ g2,
    const float* __restrict__ be2,
    const float* __restrict__ Wo,            // [N2]
    const float* __restrict__ bo,            // [1]
    float* __restrict__ out)                 // [B]
{
    __shared__ unsigned short x1s[16][N0 + 2];   // 8.3 KB
    __shared__ unsigned short h2s[16][N1 + 2];   // 4.2 KB
    __shared__ float fmld[16];
    __shared__ float partial[4][16];

    const int tid  = threadIdx.x;
    const int wq   = tid >> 6;     // wave = N-column quarter
    const int lane = tid & 63;
    const int l16  = lane & 15;
    const int quad = lane >> 4;
    const int bm   = blockIdx.x * 16;
    const int arow = bm + l16;

    // ---------------- phase 0: gather + FM + layer0 ----------------
    int idx[NF];
#pragma unroll
    for (int f = 0; f < NF; ++f)
        idx[f] = sparse[arow * NF + f] + c_offsets[f];

    float first = 0.f, sq = 0.f;
    float s8[8];
#pragma unroll
    for (int j = 0; j < 8; ++j) s8[j] = 0.f;

    if (wq == 0 && quad == 0) {
#pragma unroll
        for (int f = 0; f < NF; ++f) first += bias_tab[idx[f]];
    }

    f32x4 acc1[4];
#pragma unroll
    for (int nt = 0; nt < 4; ++nt) acc1[nt] = (f32x4){0.f, 0.f, 0.f, 0.f};

    const unsigned short* wp0 = W0b + (size_t)(wq * 64 + l16) * K0S + quad * 8;

#pragma unroll
    for (int f = 0; f < NF; ++f) {
        const float4* ep = (const float4*)(emb + (size_t)idx[f] * EMB) + quad * 2;
        float4 v0 = ep[0];
        float4 v1 = ep[1];
        if (wq == 0) {
            s8[0] += v0.x; s8[1] += v0.y; s8[2] += v0.z; s8[3] += v0.w;
            s8[4] += v1.x; s8[5] += v1.y; s8[6] += v1.z; s8[7] += v1.w;
            sq += v0.x*v0.x + v0.y*v0.y + v0.z*v0.z + v0.w*v0.w
                + v1.x*v1.x + v1.y*v1.y + v1.z*v1.z + v1.w*v1.w;
        }
        Frag a;
        a.u[0] = pk2(v0.x, v0.y); a.u[1] = pk2(v0.z, v0.w);
        a.u[2] = pk2(v1.x, v1.y); a.u[3] = pk2(v1.z, v1.w);
#pragma unroll
        for (int nt = 0; nt < 4; ++nt) {
            bf16x8 w = *(const bf16x8*)(wp0 + (size_t)(nt * 16) * K0S + f * 32);
            acc1[nt] = __builtin_amdgcn_mfma_f32_16x16x32_bf16(a.v, w, acc1[nt], 0, 0, 0);
        }
    }
    // K-step 10: dense cols 320..335 (+ zero pad to 352)
    {
        Frag a;
        if (quad < 2) {
            const float4* dp = (const float4*)(dense + arow * DENSE) + quad * 2;
            float4 v0 = dp[0];
            float4 v1 = dp[1];
            a.u[0] = pk2(v0.x, v0.y); a.u[1] = pk2(v0.z, v0.w);
            a.u[2] = pk2(v1.x, v1.y); a.u[3] = pk2(v1.z, v1.w);
        } else {
            a.u[0] = 0; a.u[1] = 0; a.u[2] = 0; a.u[3] = 0;
        }
#pragma unroll
        for (int nt = 0; nt < 4; ++nt) {
            bf16x8 w = *(const bf16x8*)(wp0 + (size_t)(nt * 16) * K0S + 320);
            acc1[nt] = __builtin_amdgcn_mfma_f32_16x16x32_bf16(a.v, w, acc1[nt], 0, 0, 0);
        }
    }

    // FM reduce across quads (only wq==0 holds data)
    if (wq == 0) {
        float ss = 0.f;
#pragma unroll
        for (int j = 0; j < 8; ++j) ss += s8[j] * s8[j];
        ss += __shfl_xor(ss, 16); ss += __shfl_xor(ss, 32);
        sq += __shfl_xor(sq, 16); sq += __shfl_xor(sq, 32);
        first += __shfl_xor(first, 16); first += __shfl_xor(first, 32);
        if (quad == 0)
            fmld[l16] = fm_bias[0] + first + 0.5f * (ss - sq);
    }

    // BN0 + ReLU -> LDS x1 tile
#pragma unroll
    for (int nt = 0; nt < 4; ++nt) {
        int col = wq * 64 + nt * 16 + l16;
        float sc = g0[col] * BN_INV;
        float tb = fmaf(b0[col], sc, be0[col]);
#pragma unroll
        for (int r = 0; r < 4; ++r) {
            float v = fmaf(acc1[nt][r], sc, tb);
            v = v > 0.f ? v : 0.f;
            x1s[quad * 4 + r][col] = f2bf(v);
        }
    }
    __syncthreads();

    // ---------------- phase 1: layer1 (256 -> 128) ----------------
    f32x4 acc2[2];
#pragma unroll
    for (int nt = 0; nt < 2; ++nt) acc2[nt] = (f32x4){0.f, 0.f, 0.f, 0.f};
    const unsigned short* wp1 = W1b + (size_t)(wq * 32 + l16) * N0 + quad * 8;
#pragma unroll
    for (int ks = 0; ks < 8; ++ks) {
        bf16x8 a = *(const bf16x8*)(&x1s[l16][ks * 32 + quad * 8]);
#pragma unroll
        for (int nt = 0; nt < 2; ++nt) {
            bf16x8 w = *(const bf16x8*)(wp1 + (size_t)(nt * 16) * N0 + ks * 32);
            acc2[nt] = __builtin_amdgcn_mfma_f32_16x16x32_bf16(a, w, acc2[nt], 0, 0, 0);
        }
    }
#pragma unroll
    for (int nt = 0; nt < 2; ++nt) {
        int col = wq * 32 + nt * 16 + l16;
        float sc = g1[col] * BN_INV;
        float tb = fmaf(b1[col], sc, be1[col]);
#pragma unroll
        for (int r = 0; r < 4; ++r) {
            float v = fmaf(acc2[nt][r], sc, tb);
            v = v > 0.f ? v : 0.f;
            h2s[quad * 4 + r][col] = f2bf(v);
        }
    }
    __syncthreads();

    // ---------------- phase 2: layer2 (128 -> 64) ----------------
    f32x4 acc3 = (f32x4){0.f, 0.f, 0.f, 0.f};
    const unsigned short* wp2 = W2b + (size_t)(wq * 16 + l16) * N1 + quad * 8;
#pragma unroll
    for (int ks = 0; ks < 4; ++ks) {
        bf16x8 a = *(const bf16x8*)(&h2s[l16][ks * 32 + quad * 8]);
        bf16x8 w = *(const bf16x8*)(wp2 + ks * 32);
        acc3 = __builtin_amdgcn_mfma_f32_16x16x32_bf16(a, w, acc3, 0, 0, 0);
    }

    // ---------------- phase 3: BN2 + ReLU + Wo-dot ----------------
    float p[4];
    {
        int col = wq * 16 + l16;
        float sc = g2[col] * BN_INV;
        float tb = fmaf(b2[col], sc, be2[col]);
        float wo = Wo[col];
#pragma unroll
        for (int r = 0; r < 4; ++r) {
            float v = fmaf(acc3[r], sc, tb);
            v = v > 0.f ? v : 0.f;
            p[r] = v * wo;
        }
    }
#pragma unroll
    for (int r = 0; r < 4; ++r) {
        p[r] += __shfl_xor(p[r], 1);
        p[r] += __shfl_xor(p[r], 2);
        p[r] += __shfl_xor(p[r], 4);
        p[r] += __shfl_xor(p[r], 8);
    }
    if (l16 == 0) {
#pragma unroll
        for (int r = 0; r < 4; ++r)
            partial[wq][quad * 4 + r] = p[r];
    }
    __syncthreads();

    if (tid < 16) {
        float z = fmld[tid] + partial[0][tid] + partial[1][tid]
                + partial[2][tid] + partial[3][tid] + bo[0];
        out[bm + tid] = 1.f / (1.f + expf(-z));
    }
}

// ---------------------------------------------------------------------------
extern "C" void kernel_launch(void* const* d_in, const int* in_sizes, int n_in,
                              void* d_out, int out_size, void* d_ws, size_t ws_size,
                              hipStream_t stream)
{
    const int*   sparse   = (const int*)  d_in[0];
    const float* dense    = (const float*)d_in[1];
    const float* emb      = (const float*)d_in[2];
    const float* bias_tab = (const float*)d_in[3];
    const float* fm_bias  = (const float*)d_in[4];
    const float* Wo       = (const float*)d_in[5];
    const float* bo       = (const float*)d_in[6];
    const float* W0 = (const float*)d_in[7];
    const float* b0 = (const float*)d_in[8];
    const float* g0 = (const float*)d_in[9];
    const float* be0= (const float*)d_in[10];
    const float* W1 = (const float*)d_in[11];
    const float* b1 = (const float*)d_in[12];
    const float* g1 = (const float*)d_in[13];
    const float* be1= (const float*)d_in[14];
    const float* W2 = (const float*)d_in[15];
    const float* b2 = (const float*)d_in[16];
    const float* g2 = (const float*)d_in[17];
    const float* be2= (const float*)d_in[18];

    float* out = (float*)d_out;

    // workspace: converted weights only (256 KB)
    char* p = (char*)d_ws;
    unsigned short* W0b = (unsigned short*)p; p += (size_t)N0 * K0S * 2;
    unsigned short* W1b = (unsigned short*)p; p += (size_t)N1 * N0 * 2;
    unsigned short* W2b = (unsigned short*)p; p += (size_t)N2 * N1 * 2;

    k_wconv_all<<<(N0 * K0S + N1 * N0 + N2 * N1) / 256, 256, 0, stream>>>(
        W0, W1, W2, W0b, W1b, W2b);

    k_fused_all<<<BROWS / 16, 256, 0, stream>>>(
        sparse, dense, emb, bias_tab, fm_bias,
        W0b, b0, g0, be0, W1b, b1, g1, be1, W2b, b2, g2, be2,
        Wo, bo, out);
}

// Round 6
// 235.012 us; speedup vs baseline: 1.0293x; 1.0293x over previous
//
#include <hip/hip_runtime.h>
#include <hip/hip_bf16.h>
#include <math.h>

// ---- problem constants ----
#define BROWS 16384
#define NF    10
#define EMB   32
#define DENSE 16
#define K0S   352   // 336 padded to 11 K-steps of 32
#define K0    336
#define N0    256
#define N1    128
#define N2    64
#define BN_INV 0.99999500003749969f  // 1/sqrt(1+1e-5)

__constant__ int c_offsets[NF] = {
    0, 1000000, 1100000, 1101008, 1102012,
    1102114, 1103114, 1103614, 1103664, 1103776
};

typedef short  bf16x8 __attribute__((ext_vector_type(8)));
typedef float  f32x4  __attribute__((ext_vector_type(4)));

union Frag { bf16x8 v; unsigned u[4]; };

static __device__ __forceinline__ unsigned short f2bf(float x) {
    union { float f; unsigned u; } c; c.f = x;
    unsigned r = (c.u + 0x7FFFu + ((c.u >> 16) & 1u)) >> 16;  // RNE
    return (unsigned short)r;
}
// hw v_cvt_pk_bf16_f32 on gfx950 (RNE)
static __device__ __forceinline__ unsigned pk2(float x, float y) {
    __hip_bfloat162 h = __float22bfloat162_rn(make_float2(x, y));
    union { __hip_bfloat162 h; unsigned u; } c; c.h = h; return c.u;
}

// ---------------------------------------------------------------------------
// Weight fp32 -> bf16 conversion (W0 K-padded 336->352). 131072 elements.
// ---------------------------------------------------------------------------
__global__ __launch_bounds__(256) void k_wconv_all(
    const float* __restrict__ W0, const float* __restrict__ W1,
    const float* __restrict__ W2,
    unsigned short* __restrict__ W0b, unsigned short* __restrict__ W1b,
    unsigned short* __restrict__ W2b)
{
    int i = blockIdx.x * 256 + threadIdx.x;
    if (i < N0 * K0S) {
        int r = i / K0S, c = i - r * K0S;
        W0b[i] = f2bf(c < K0 ? W0[r * K0 + c] : 0.f);
    } else if (i < N0 * K0S + N1 * N0) {
        int j = i - N0 * K0S;
        W1b[j] = f2bf(W1[j]);
    } else {
        int j = i - (N0 * K0S + N1 * N0);
        W2b[j] = f2bf(W2[j]);
    }
}

// ---------------------------------------------------------------------------
// Single fused kernel: gather + FM + L0 + L1 + L2 + out-dot + sigmoid.
// block = 256 thr = 4 waves, 32 batch rows per block, grid = 512 (2 blk/CU).
// wave -> (rg = wave&1: row group of 16, hh = wave>>1: N-column half).
// All intermediates in LDS. R4 structure + hw bf16 pack + distributed
// first-order gathers.
// MFMA 16x16x32 bf16: A[m=l16][k=quad*8+j]; B-frag = W[n=l16][k=...];
// C/D: col=l16, row=quad*4+reg.
// ---------------------------------------------------------------------------
__global__ __launch_bounds__(256) void k_fused_all(
    const int*   __restrict__ sparse,    // [B, NF]
    const float* __restrict__ dense,     // [B, DENSE]
    const float* __restrict__ emb,       // [V, EMB]
    const float* __restrict__ bias_tab,  // [V]
    const float* __restrict__ fm_bias,   // [1]
    const unsigned short* __restrict__ W0b,  // [N0, K0S]
    const float* __restrict__ b0, const float* __restrict__ g0,
    const float* __restrict__ be0,
    const unsigned short* __restrict__ W1b,  // [N1, N0]
    const float* __restrict__ b1, const float* __restrict__ g1,
    const float* __restrict__ be1,
    const unsigned short* __restrict__ W2b,  // [N2, N1]
    const float* __restrict__ b2, const float* __restrict__ g2,
    const float* __restrict__ be2,
    const float* __restrict__ Wo,            // [N2]
    const float* __restrict__ bo,            // [1]
    float* __restrict__ out)                 // [B]
{
    __shared__ unsigned short x1s[32][N0 + 2];   // stride 258 shorts
    __shared__ unsigned short h2s[32][N1 + 2];
    __shared__ float fmld[32];
    __shared__ float partial[2][32];

    const int tid  = threadIdx.x;
    const int wave = tid >> 6;
    const int lane = tid & 63;
    const int l16  = lane & 15;
    const int quad = lane >> 4;
    const int rg   = wave & 1;     // row group (16 rows)
    const int hh   = wave >> 1;    // N-column half
    const int bm   = blockIdx.x * 32;
    const int arow = bm + rg * 16 + l16;

    // ---------------- phase 0: gather + FM + layer0 ----------------
    int idx[NF];
#pragma unroll
    for (int f = 0; f < NF; ++f)
        idx[f] = sparse[arow * NF + f] + c_offsets[f];

    float first = 0.f, sq = 0.f;
    float s8[8];
#pragma unroll
    for (int j = 0; j < 8; ++j) s8[j] = 0.f;

    // first-order gathers distributed across quads (reduced by shfl below)
    if (hh == 0) {
#pragma unroll
        for (int f = 0; f < NF; ++f)
            if ((f & 3) == quad) first += bias_tab[idx[f]];
    }

    f32x4 acc1[8];
#pragma unroll
    for (int nt = 0; nt < 8; ++nt) acc1[nt] = (f32x4){0.f, 0.f, 0.f, 0.f};

    const unsigned short* wp0 = W0b + (size_t)(hh * 128 + l16) * K0S + quad * 8;

#pragma unroll
    for (int f = 0; f < NF; ++f) {
        const float4* ep = (const float4*)(emb + (size_t)idx[f] * EMB) + quad * 2;
        float4 v0 = ep[0];
        float4 v1 = ep[1];
        if (hh == 0) {
            s8[0] += v0.x; s8[1] += v0.y; s8[2] += v0.z; s8[3] += v0.w;
            s8[4] += v1.x; s8[5] += v1.y; s8[6] += v1.z; s8[7] += v1.w;
            sq += v0.x*v0.x + v0.y*v0.y + v0.z*v0.z + v0.w*v0.w
                + v1.x*v1.x + v1.y*v1.y + v1.z*v1.z + v1.w*v1.w;
        }
        Frag a;
        a.u[0] = pk2(v0.x, v0.y); a.u[1] = pk2(v0.z, v0.w);
        a.u[2] = pk2(v1.x, v1.y); a.u[3] = pk2(v1.z, v1.w);
#pragma unroll
        for (int nt = 0; nt < 8; ++nt) {
            bf16x8 w = *(const bf16x8*)(wp0 + (size_t)(nt * 16) * K0S + f * 32);
            acc1[nt] = __builtin_amdgcn_mfma_f32_16x16x32_bf16(a.v, w, acc1[nt], 0, 0, 0);
        }
    }
    // K-step 10: dense cols 320..335 (+ zero pad to 352)
    {
        Frag a;
        if (quad < 2) {
            const float4* dp = (const float4*)(dense + arow * DENSE) + quad * 2;
            float4 v0 = dp[0];
            float4 v1 = dp[1];
            a.u[0] = pk2(v0.x, v0.y); a.u[1] = pk2(v0.z, v0.w);
            a.u[2] = pk2(v1.x, v1.y); a.u[3] = pk2(v1.z, v1.w);
        } else {
            a.u[0] = 0; a.u[1] = 0; a.u[2] = 0; a.u[3] = 0;
        }
#pragma unroll
        for (int nt = 0; nt < 8; ++nt) {
            bf16x8 w = *(const bf16x8*)(wp0 + (size_t)(nt * 16) * K0S + 320);
            acc1[nt] = __builtin_amdgcn_mfma_f32_16x16x32_bf16(a.v, w, acc1[nt], 0, 0, 0);
        }
    }

    // FM reduce across quads (only hh==0 holds data)
    if (hh == 0) {
        float ss = 0.f;
#pragma unroll
        for (int j = 0; j < 8; ++j) ss += s8[j] * s8[j];
        ss += __shfl_xor(ss, 16); ss += __shfl_xor(ss, 32);
        sq += __shfl_xor(sq, 16); sq += __shfl_xor(sq, 32);
        first += __shfl_xor(first, 16); first += __shfl_xor(first, 32);
        if (quad == 0)
            fmld[rg * 16 + l16] = fm_bias[0] + first + 0.5f * (ss - sq);
    }

    // BN0 + ReLU -> LDS x1 tile
#pragma unroll
    for (int nt = 0; nt < 8; ++nt) {
        int col = hh * 128 + nt * 16 + l16;
        float sc = g0[col] * BN_INV;
        float tb = fmaf(b0[col], sc, be0[col]);
#pragma unroll
        for (int r = 0; r < 4; ++r) {
            float v = fmaf(acc1[nt][r], sc, tb);
            v = v > 0.f ? v : 0.f;
            x1s[rg * 16 + quad * 4 + r][col] = f2bf(v);
        }
    }
    __syncthreads();

    // ---------------- phase 1: layer1 (256 -> 128) ----------------
    f32x4 acc2[4];
#pragma unroll
    for (int nt = 0; nt < 4; ++nt) acc2[nt] = (f32x4){0.f, 0.f, 0.f, 0.f};
    const unsigned short* wp1 = W1b + (size_t)(hh * 64 + l16) * N0 + quad * 8;
#pragma unroll
    for (int ks = 0; ks < 8; ++ks) {
        bf16x8 a = *(const bf16x8*)(&x1s[rg * 16 + l16][ks * 32 + quad * 8]);
#pragma unroll
        for (int nt = 0; nt < 4; ++nt) {
            bf16x8 w = *(const bf16x8*)(wp1 + (size_t)(nt * 16) * N0 + ks * 32);
            acc2[nt] = __builtin_amdgcn_mfma_f32_16x16x32_bf16(a, w, acc2[nt], 0, 0, 0);
        }
    }
#pragma unroll
    for (int nt = 0; nt < 4; ++nt) {
        int col = hh * 64 + nt * 16 + l16;
        float sc = g1[col] * BN_INV;
        float tb = fmaf(b1[col], sc, be1[col]);
#pragma unroll
        for (int r = 0; r < 4; ++r) {
            float v = fmaf(acc2[nt][r], sc, tb);
            v = v > 0.f ? v : 0.f;
            h2s[rg * 16 + quad * 4 + r][col] = f2bf(v);
        }
    }
    __syncthreads();

    // ---------------- phase 2: layer2 (128 -> 64) ----------------
    f32x4 acc3[2];
#pragma unroll
    for (int nt = 0; nt < 2; ++nt) acc3[nt] = (f32x4){0.f, 0.f, 0.f, 0.f};
    const unsigned short* wp2 = W2b + (size_t)(hh * 32 + l16) * N1 + quad * 8;
#pragma unroll
    for (int ks = 0; ks < 4; ++ks) {
        bf16x8 a = *(const bf16x8*)(&h2s[rg * 16 + l16][ks * 32 + quad * 8]);
#pragma unroll
        for (int nt = 0; nt < 2; ++nt) {
            bf16x8 w = *(const bf16x8*)(wp2 + (size_t)(nt * 16) * N1 + ks * 32);
            acc3[nt] = __builtin_amdgcn_mfma_f32_16x16x32_bf16(a, w, acc3[nt], 0, 0, 0);
        }
    }

    // ---------------- phase 3: BN2 + ReLU + Wo-dot + sigmoid ----------------
    float p[4] = {0.f, 0.f, 0.f, 0.f};
#pragma unroll
    for (int nt = 0; nt < 2; ++nt) {
        int col = hh * 32 + nt * 16 + l16;
        float sc = g2[col] * BN_INV;
        float tb = fmaf(b2[col], sc, be2[col]);
        float wo = Wo[col];
#pragma unroll
        for (int r = 0; r < 4; ++r) {
            float v = fmaf(acc3[nt][r], sc, tb);
            v = v > 0.f ? v : 0.f;
            p[r] = fmaf(v, wo, p[r]);
        }
    }
#pragma unroll
    for (int r = 0; r < 4; ++r) {
        p[r] += __shfl_xor(p[r], 1);
        p[r] += __shfl_xor(p[r], 2);
        p[r] += __shfl_xor(p[r], 4);
        p[r] += __shfl_xor(p[r], 8);
    }
    if (l16 == 0) {
#pragma unroll
        for (int r = 0; r < 4; ++r)
            partial[hh][rg * 16 + quad * 4 + r] = p[r];
    }
    __syncthreads();

    if (tid < 32) {
        float z = fmld[tid] + partial[0][tid] + partial[1][tid] + bo[0];
        out[bm + tid] = 1.f / (1.f + expf(-z));
    }
}

// ---------------------------------------------------------------------------
extern "C" void kernel_launch(void* const* d_in, const int* in_sizes, int n_in,
                              void* d_out, int out_size, void* d_ws, size_t ws_size,
                              hipStream_t stream)
{
    const int*   sparse   = (const int*)  d_in[0];
    const float* dense    = (const float*)d_in[1];
    const float* emb      = (const float*)d_in[2];
    const float* bias_tab = (const float*)d_in[3];
    const float* fm_bias  = (const float*)d_in[4];
    const float* Wo       = (const float*)d_in[5];
    const float* bo       = (const float*)d_in[6];
    const float* W0 = (const float*)d_in[7];
    const float* b0 = (const float*)d_in[8];
    const float* g0 = (const float*)d_in[9];
    const float* be0= (const float*)d_in[10];
    const float* W1 = (const float*)d_in[11];
    const float* b1 = (const float*)d_in[12];
    const float* g1 = (const float*)d_in[13];
    const float* be1= (const float*)d_in[14];
    const float* W2 = (const float*)d_in[15];
    const float* b2 = (const float*)d_in[16];
    const float* g2 = (const float*)d_in[17];
    const float* be2= (const float*)d_in[18];

    float* out = (float*)d_out;

    // workspace: converted weights only (256 KB)
    char* p = (char*)d_ws;
    unsigned short* W0b = (unsigned short*)p; p += (size_t)N0 * K0S * 2;
    unsigned short* W1b = (unsigned short*)p; p += (size_t)N1 * N0 * 2;
    unsigned short* W2b = (unsigned short*)p; p += (size_t)N2 * N1 * 2;

    k_wconv_all<<<(N0 * K0S + N1 * N0 + N2 * N1) / 256, 256, 0, stream>>>(
        W0, W1, W2, W0b, W1b, W2b);

    k_fused_all<<<BROWS / 32, 256, 0, stream>>>(
        sparse, dense, emb, bias_tab, fm_bias,
        W0b, b0, g0, be0, W1b, b1, g1, be1, W2b, b2, g2, be2,
        Wo, bo, out);
}